// Round 19
// baseline (891.537 us; speedup 1.0000x reference)
//
#include <hip/hip_runtime.h>
#include <cmath>

typedef unsigned int u32;
typedef unsigned long long u64;
typedef _Float16 f16;
typedef _Float16 f16x8 __attribute__((ext_vector_type(8)));
typedef float f32x4 __attribute__((ext_vector_type(4)));

// address-space-qualified typedefs for global_load_lds
typedef __attribute__((address_space(1))) const unsigned int gu32;
typedef __attribute__((address_space(3))) unsigned int lu32;

#define NCAND 4507
#define WORDS 71              // ceil(4507/64)
#define ROWS_AL (WORDS * 64)  // 4544
#define TOTS 159882           // total scores across levels
#define NTILES 863
#define CONVGRID 768

__constant__ int c_W[5]      = {200, 100, 50, 25, 13};
__constant__ int c_stride[5] = {4, 8, 16, 32, 61};
__constant__ int c_Nl[5]     = {120000, 30000, 7500, 1875, 507};
__constant__ int c_soff[5]   = {0, 120000, 150000, 157500, 159375};
__constant__ int c_k[5]      = {1000, 1000, 1000, 1000, 507};

// unified conv grid: tiles per level (8x8 px tiles): 625,169,49,16,4
__constant__ int cv_boff[6]  = {0, 625, 794, 843, 859, 863};

struct DecParams { float b[5][3][4]; };
struct FeatPtrs { const float* p[5]; };

__device__ __forceinline__ u32 flipf(float f) {
    u32 u = __float_as_uint(f);
    return (u & 0x80000000u) ? ~u : (u | 0x80000000u);
}

// ---------------- workspace layout ----------------
constexpr size_t AL(size_t x) { return (x + 255) & ~(size_t)255; }
constexpr size_t OFF_WHI    = 0;                                   // 589824 f16
constexpr size_t OFF_WLO    = AL(OFF_WHI + 1179648);               // 589824 f16
constexpr size_t OFF_HEADW  = AL(OFF_WLO + 1179648);               // 15*256 f
constexpr size_t OFF_HEADB  = AL(OFF_HEADW + 3840 * 4);            // 15 f
constexpr size_t OFF_SCORES = AL(OFF_HEADB + 64);                  // TOTS f
constexpr size_t OFF_DELTAS = AL(OFF_SCORES + (size_t)TOTS * 4);   // TOTS*4 f
constexpr size_t OFF_SBOX   = AL(OFF_DELTAS + (size_t)TOTS * 16);  // NCAND*4 f
constexpr size_t OFF_SOB    = AL(OFF_SBOX + (size_t)NCAND * 16);   // NCAND*4 f
constexpr size_t OFF_SVAL   = AL(OFF_SOB + (size_t)NCAND * 16);    // NCAND u32
constexpr size_t OFF_MASK   = AL(OFF_SVAL + (size_t)NCAND * 4);    // ROWS_AL*WORDS u64 (2.58 MB)
constexpr size_t OFF_KEEP   = AL(OFF_MASK + (size_t)ROWS_AL * WORDS * 8); // WORDS u64
constexpr size_t OFF_GHIST  = AL(OFF_KEEP + WORDS * 8);            // 5*256 u32
constexpr size_t OFF_CNT    = AL(OFF_GHIST + 1280 * 4);            // 16 u32 (sel 0..4, tie 8..11, done 12/13)
constexpr size_t OFF_KEY    = AL(OFF_CNT + 64);                    // 5000 u64
// classify/finish use the MASK region as tie scratch (2x TOTS u64 <= 2.58 MB);
// safe: mask phase fully rewrites MASK afterwards (separate dispatch).

// ---------------- kernel 1: weight prep (OUTPUT-LINEAR, coalesced) + state zeroing ----------------
__global__ __launch_bounds__(256) void k_prep(
    const float* __restrict__ cw, const float* __restrict__ clsw,
    const float* __restrict__ clsb, const float* __restrict__ bw,
    const float* __restrict__ bb, f16* __restrict__ whi, f16* __restrict__ wlo,
    float* __restrict__ headw, float* __restrict__ headb,
    u32* __restrict__ ghist, u32* __restrict__ cnts) {
    int i = blockIdx.x * 256 + threadIdx.x;
    if (i < 589824) {
        int blk = i >> 13;          // 72 blocks of 8192 f16
        int within = i & 8191;
        int co = within >> 5;
        int rem = within & 31;
        int slot = rem >> 3, j = rem & 7;
        int chunk = blk / 9, kk = blk - chunk * 9;
        int ky = kk / 3, kx = kk - ky * 3;
        int g = slot ^ ((co >> 1) & 3);
        int ci = (chunk << 5) | (g << 3) | j;
        float w = cw[(((co << 8) + ci) * 3 + ky) * 3 + kx];
        f16 hi = (f16)w;
        whi[i] = hi;
        wlo[i] = (f16)((w - (float)hi) * 2048.0f);
    }
    if (i < 3840) {
        int h = i >> 8, ci = i & 255;
        headw[i] = (h < 3) ? clsw[h * 256 + ci] : bw[(h - 3) * 256 + ci];
    }
    if (i < 15) headb[i] = (i < 3) ? clsb[i] : bb[i - 3];
    if (i < 1280) ghist[i] = 0;
    if (i < 16) cnts[i] = 0;
}

// ---------------- kernel 2: MFMA fp16-split conv + heads + fused score hist ----------------
// v3 (r19): HYBRID B-path for 3 blocks/CU. whi staged via the proven 2-deep
// global_load_lds pipeline (2x16KB dbuf); wlo fragments read DIRECTLY from
// L2-resident global per step (only 2 exposed loads/step; 8 of 12 MFMAs per
// nt-pair are vbl-independent -> ~230cy cover vs ~200cy L2 latency, plus +50%
// TLP from the 3rd block). LDS 78.3 -> 45.6 KB. Numerics bit-identical.
// Conv-structure ledger: r16 (full dbuf, 2/CU) = 408us; r17 (all-direct) = 444.
__global__ __launch_bounds__(512) void k_conv(
    FeatPtrs fp, const f16* __restrict__ whi, const f16* __restrict__ wlo,
    const float* __restrict__ convb, const float* __restrict__ headw,
    const float* __restrict__ headb, float* __restrict__ scores,
    float* __restrict__ deltas, u32* __restrict__ ghist) {
    __shared__ float4 smq[2848];  // 45568 B: A hi/lo 2x6400 @0, B-hi dbuf 2x16384 @12800
    char* smb = (char*)smq;
    const int tid = threadIdx.x;
    const int lane = tid & 63, wv = tid >> 6;
    const int l15 = lane & 15, l4 = lane >> 4;

    int rbase0, rbase1, rbase2, rbase3;
    {
        int rr = l15 >> 3;
        rbase0 = (0 + rr) * 640; rbase1 = (2 + rr) * 640;
        rbase2 = (4 + rr) * 640; rbase3 = (6 + rr) * 640;
    }
    int colx0, colx1, colx2;
    {
        int c = lane & 7;
        int p0 = c, p1 = c + 1, p2 = c + 2;
        colx0 = p0 * 64 + ((l4 ^ ((p0 >> 1) & 3)) << 4);
        colx1 = p1 * 64 + ((l4 ^ ((p1 >> 1) & 3)) << 4);
        colx2 = p2 * 64 + ((l4 ^ ((p2 >> 1) & 3)) << 4);
    }
    const int bco0 = wv * 32 + l15, bco1 = wv * 32 + 16 + l15;
    const int boff0 = bco0 * 64 + ((l4 ^ ((bco0 >> 1) & 3)) << 4);
    const int boff1 = bco1 * 64 + ((l4 ^ ((bco1 >> 1) & 3)) << 4);

    for (int bt = blockIdx.x; bt < NTILES; bt += gridDim.x) {
        int l = 0;
#pragma unroll
        for (int q = 1; q < 5; q++) if (bt >= cv_boff[q]) l = q;
        const int H = c_W[l], W = H;
        const int soff = c_soff[l];
        const float* __restrict__ in = fp.p[l];
        const int t = bt - cv_boff[l];
        const int tilesx = (W + 7) >> 3;
        const int tx = t % tilesx, ty = t / tilesx;
        const int x0 = tx * 8, y0 = ty * 8;
        const int HW = H * W;

        f32x4 acc1[4][2], acc2[4][2];
#pragma unroll
        for (int mt = 0; mt < 4; mt++)
#pragma unroll
            for (int nt = 0; nt < 2; nt++) {
                acc1[mt][nt] = (f32x4)0.0f;
                acc2[mt][nt] = (f32x4)0.0f;
            }

        auto stagePatch = [&](int chunk) {
            const int c0 = chunk << 5;
            f16* ph = (f16*)smb;
            f16* pl = (f16*)(smb + 6400);
            for (int e = tid; e < 3200; e += 512) {
                int py = e / 320, rem = e - py * 320;
                int px = rem >> 5, ci = rem & 31;
                int gy = y0 - 1 + py, gx = x0 - 1 + px;
                float v = 0.f;
                if (gy >= 0 && gy < H && gx >= 0 && gx < W)
                    v = in[(c0 + ci) * HW + gy * W + gx];
                f16 hi = (f16)v;
                int widx = py * 320 + px * 32 + (((ci >> 3) ^ ((px >> 1) & 3)) << 3) + (ci & 7);
                ph[widx] = hi;
                pl[widx] = (f16)((v - (float)hi) * 2048.0f);
            }
        };
        auto issueB = [&](int sidx, int buf) {   // hi only (16KB)
            const char* gh = (const char*)whi + (size_t)sidx * 16384;
            char* dh = smb + 12800 + buf * 16384;
#pragma unroll
            for (int q = 0; q < 2; q++) {
                int i1 = (wv * 2 + q) * 1024;
                __builtin_amdgcn_global_load_lds((gu32*)(gh + i1 + lane * 16), (lu32*)(dh + i1), 16, 0, 0);
            }
        };

        stagePatch(0);
        issueB(0, 0);
        __syncthreads();

        for (int chunk = 0; chunk < 8; ++chunk) {
            if (chunk) { stagePatch(chunk); __syncthreads(); }
#pragma unroll
            for (int kk = 0; kk < 9; ++kk) {
                const int s = chunk * 9 + kk;
                const int buf = s & 1;
                if (s < 71) issueB(s + 1, buf ^ 1);
                {
                    const int ky = kk / 3, kx = kk - ky * 3;
                    const int kyb = ky * 640;
                    const int cx = (kx == 0) ? colx0 : (kx == 1) ? colx1 : colx2;
                    const char* bh = smb + 12800 + buf * 16384;
                    const char* gbl = (const char*)wlo + (size_t)s * 16384;
                    f16x8 ah0 = *(const f16x8*)(smb + rbase0 + kyb + cx);
                    f16x8 ah1 = *(const f16x8*)(smb + rbase1 + kyb + cx);
                    f16x8 ah2 = *(const f16x8*)(smb + rbase2 + kyb + cx);
                    f16x8 ah3 = *(const f16x8*)(smb + rbase3 + kyb + cx);
                    f16x8 al0 = *(const f16x8*)(smb + 6400 + rbase0 + kyb + cx);
                    f16x8 al1 = *(const f16x8*)(smb + 6400 + rbase1 + kyb + cx);
                    f16x8 al2 = *(const f16x8*)(smb + 6400 + rbase2 + kyb + cx);
                    f16x8 al3 = *(const f16x8*)(smb + 6400 + rbase3 + kyb + cx);
#pragma unroll
                    for (int nt = 0; nt < 2; nt++) {
                        const int bo = nt ? boff1 : boff0;
                        f16x8 vbh = *(const f16x8*)(bh + bo);
                        f16x8 vbl = *(const f16x8*)(gbl + bo);   // direct from L2
                        // vbl-independent MFMAs first (cover the L2 latency)
                        acc1[0][nt] = __builtin_amdgcn_mfma_f32_16x16x32_f16(ah0, vbh, acc1[0][nt], 0, 0, 0);
                        acc2[0][nt] = __builtin_amdgcn_mfma_f32_16x16x32_f16(al0, vbh, acc2[0][nt], 0, 0, 0);
                        acc1[1][nt] = __builtin_amdgcn_mfma_f32_16x16x32_f16(ah1, vbh, acc1[1][nt], 0, 0, 0);
                        acc2[1][nt] = __builtin_amdgcn_mfma_f32_16x16x32_f16(al1, vbh, acc2[1][nt], 0, 0, 0);
                        acc1[2][nt] = __builtin_amdgcn_mfma_f32_16x16x32_f16(ah2, vbh, acc1[2][nt], 0, 0, 0);
                        acc2[2][nt] = __builtin_amdgcn_mfma_f32_16x16x32_f16(al2, vbh, acc2[2][nt], 0, 0, 0);
                        acc1[3][nt] = __builtin_amdgcn_mfma_f32_16x16x32_f16(ah3, vbh, acc1[3][nt], 0, 0, 0);
                        acc2[3][nt] = __builtin_amdgcn_mfma_f32_16x16x32_f16(al3, vbh, acc2[3][nt], 0, 0, 0);
                        acc2[0][nt] = __builtin_amdgcn_mfma_f32_16x16x32_f16(ah0, vbl, acc2[0][nt], 0, 0, 0);
                        acc2[1][nt] = __builtin_amdgcn_mfma_f32_16x16x32_f16(ah1, vbl, acc2[1][nt], 0, 0, 0);
                        acc2[2][nt] = __builtin_amdgcn_mfma_f32_16x16x32_f16(ah2, vbl, acc2[2][nt], 0, 0, 0);
                        acc2[3][nt] = __builtin_amdgcn_mfma_f32_16x16x32_f16(ah3, vbl, acc2[3][nt], 0, 0, 0);
                    }
                }
                __syncthreads();
            }
        }

        const float INV2048 = 4.8828125e-4f;
        {
            float cb0 = convb[bco0], cb1 = convb[bco1];
#pragma unroll
            for (int mt = 0; mt < 4; mt++)
#pragma unroll
                for (int nt = 0; nt < 2; nt++) {
                    float cb = nt ? cb1 : cb0;
#pragma unroll
                    for (int r = 0; r < 4; r++) {
                        float tv = acc1[mt][nt][r] + acc2[mt][nt][r] * INV2048 + cb;
                        acc1[mt][nt][r] = tv > 0.f ? tv : 0.f;
                    }
                }
        }

        u32* lhist = (u32*)(smb + 12800);
        for (int i = tid; i < 1280; i += 512) lhist[i] = 0;

        float* part = (float*)smb;  // [8 wv][64 px][3]
        for (int hc = 0; hc < 15; hc += 3) {
            float hw3[3][2];
#pragma unroll
            for (int h3 = 0; h3 < 3; h3++) {
                hw3[h3][0] = headw[(hc + h3) * 256 + bco0];
                hw3[h3][1] = headw[(hc + h3) * 256 + bco1];
            }
#pragma unroll
            for (int mt = 0; mt < 4; mt++)
#pragma unroll
                for (int r = 0; r < 4; r++) {
                    float p0 = 0.f, p1 = 0.f, p2 = 0.f;
#pragma unroll
                    for (int nt = 0; nt < 2; nt++) {
                        float tv = acc1[mt][nt][r];
                        p0 = fmaf(hw3[0][nt], tv, p0);
                        p1 = fmaf(hw3[1][nt], tv, p1);
                        p2 = fmaf(hw3[2][nt], tv, p2);
                    }
                    p0 += __shfl_xor(p0, 1); p0 += __shfl_xor(p0, 2); p0 += __shfl_xor(p0, 4); p0 += __shfl_xor(p0, 8);
                    p1 += __shfl_xor(p1, 1); p1 += __shfl_xor(p1, 2); p1 += __shfl_xor(p1, 4); p1 += __shfl_xor(p1, 8);
                    p2 += __shfl_xor(p2, 1); p2 += __shfl_xor(p2, 2); p2 += __shfl_xor(p2, 4); p2 += __shfl_xor(p2, 8);
                    if (l15 == 0) {
                        int px = mt * 16 + l4 * 4 + r;
                        part[(wv * 64 + px) * 3 + 0] = p0;
                        part[(wv * 64 + px) * 3 + 1] = p1;
                        part[(wv * 64 + px) * 3 + 2] = p2;
                    }
                }
            __syncthreads();
            if (tid < 192) {
                int px = tid / 3, h3 = tid % 3;
                int h = hc + h3;
                float sum = 0.f;
#pragma unroll
                for (int g = 0; g < 8; g++) sum += part[(g * 64 + px) * 3 + h3];
                sum += headb[h];
                int gy = y0 + (px >> 3), gx = x0 + (px & 7);
                if (gy < H && gx < W) {
                    int pix = gy * W + gx;
                    if (h < 3) {
                        scores[soff + pix * 3 + h] = sum;
                        atomicAdd(&lhist[l * 256 + (flipf(sum) >> 24)], 1u);
                    } else {
                        int ch2 = h - 3;
                        deltas[((size_t)(soff + pix * 3 + (ch2 >> 2))) * 4 + (ch2 & 3)] = sum;
                    }
                }
            }
            __syncthreads();
        }
        for (int i = tid; i < 1280; i += 512) {
            u32 v = lhist[i];
            if (v) atomicAdd(&ghist[i], v);
        }
        __syncthreads();
    }
}

// ---------------- kernel 3: classify (chip-parallel) + last-block finish (r16, unchanged) ----------------
__global__ __launch_bounds__(1024) void k_clsfin(
    const float* __restrict__ scores, const u32* __restrict__ ghist,
    u64* __restrict__ key, u64* __restrict__ scr1, u64* __restrict__ scr2,
    u32* __restrict__ cnts, const float* __restrict__ deltas, DecParams P,
    float* __restrict__ sboxes, float* __restrict__ sob, u32* __restrict__ svalid) {
    __shared__ u64 sk[8192];
    __shared__ u32 lh[1280];
    __shared__ u32 tiebuf[2048];
    __shared__ u32 sb0[5];
    __shared__ u32 sh_sel, sh_t1, sh_t2, sh_m, sh_last;
    const int tid = threadIdx.x;
    const int lane = tid & 63;

    for (int i = tid; i < 1280; i += 1024) lh[i] = ghist[i];
    __syncthreads();
    if (tid < 4) {
        int l = tid;
        u32 m0 = (u32)c_k[l];
        u32 cum = 0;
        for (int b = 255; b >= 0; --b) {
            u32 c = lh[l * 256 + b];
            if (cum + c >= m0) { sb0[l] = (u32)b; break; }
            cum += c;
        }
    }
    __syncthreads();
    const int gsz = gridDim.x * 1024;
    for (int i = blockIdx.x * 1024 + tid; i < TOTS; i += gsz) {
        int l = (i >= 120000) + (i >= 150000) + (i >= 157500) + (i >= 159375);
        u32 il = (u32)(i - c_soff[l]);
        u32 k32 = flipf(scores[i]);
        u32 b = k32 >> 24;
        bool sel = (l == 4) || (b > sb0[l]);
        bool tie = (l < 4) && (b == sb0[l]);
        u64 m1 = __ballot(sel);
        while (m1) {
            int ldr = __builtin_ctzll(m1);
            int lv = __shfl(l, ldr);
            u64 grp = __ballot(sel && (l == lv));
            u32 bs = 0;
            if (lane == ldr) bs = atomicAdd(&cnts[lv], (u32)__popcll(grp));
            bs = __shfl(bs, ldr);
            if (sel && l == lv) {
                u32 slot = bs + (u32)__popcll(grp & ((1ull << lane) - 1ull));
                key[lv * 1000 + slot] = ((u64)(~k32) << 32) | (u64)(((u32)lv << 24) | il);
            }
            m1 &= ~grp;
        }
        u64 m2 = __ballot(tie);
        while (m2) {
            int ldr = __builtin_ctzll(m2);
            int lv = __shfl(l, ldr);
            u64 grp = __ballot(tie && (l == lv));
            u32 bs = 0;
            if (lane == ldr) bs = atomicAdd(&cnts[8 + lv], (u32)__popcll(grp));
            bs = __shfl(bs, ldr);
            if (tie && l == lv) {
                u32 slot = bs + (u32)__popcll(grp & ((1ull << lane) - 1ull));
                scr1[c_soff[lv] + slot] = ((u64)k32 << 32) | (u64)il;
            }
            m2 &= ~grp;
        }
    }
    __threadfence();
    if (tid == 0) sh_last = (atomicAdd(&cnts[12], 1u) == gridDim.x - 1) ? 1u : 0u;
    __syncthreads();
    if (!sh_last) return;
    __threadfence();

    u32* hist = lh;
    for (int l = 0; l < 5; ++l) {
        u32 n = cnts[l];
        int base = l * 1000;
        for (u32 j = tid; j < n; j += 1024) sk[base + j] = key[base + j];
    }
    __syncthreads();
    for (int l = 0; l < 4; ++l) {
        const int off = c_soff[l], base = l * 1000;
        const u32 lshift = (u32)l << 24;
        u32 nsel = cnts[l];
        u32 m = (u32)c_k[l] - nsel;
        u32 n = cnts[8 + l];
        u64* curb = scr1 + off;
        u64* nxtb = scr2 + off;
        if (tid == 0) sh_sel = nsel;
        __syncthreads();
        for (int p = 1; p <= 3; ++p) {
            if (n == m) break;
            const int shift = 56 - 8 * p;
            for (int b = tid; b < 256; b += 1024) hist[b] = 0;
            if (tid == 0) sh_t1 = 0;
            __syncthreads();
            for (u32 j = tid; j < n; j += 1024)
                atomicAdd(&hist[(u32)(curb[j] >> shift) & 255u], 1u);
            __syncthreads();
            if (tid == 0) {
                u32 cum = 0;
                for (int b = 255; b >= 0; --b) {
                    u32 c = hist[b];
                    if (cum + c >= m) { sh_t2 = (u32)b; sh_m = m - cum; break; }
                    cum += c;
                }
            }
            __syncthreads();
            u32 bp = sh_t2; m = sh_m;
            for (u32 j = tid; j < n; j += 1024) {
                u64 e = curb[j];
                u32 b = (u32)(e >> shift) & 255u;
                bool sel = b > bp, tie = (b == bp);
                u64 msk = __ballot(sel);
                if (msk) {
                    int ldr = __builtin_ctzll(msk);
                    u32 bs = 0;
                    if (lane == ldr) bs = atomicAdd(&sh_sel, (u32)__popcll(msk));
                    bs = __shfl(bs, ldr);
                    if (sel) {
                        u32 slot = bs + (u32)__popcll(msk & ((1ull << lane) - 1ull));
                        u32 k32 = (u32)(e >> 32);
                        sk[base + slot] = ((u64)(~k32) << 32) | (u64)(lshift | (u32)(e & 0xFFFFFFu));
                    }
                }
                msk = __ballot(tie);
                if (msk) {
                    int ldr = __builtin_ctzll(msk);
                    u32 bs = 0;
                    if (lane == ldr) bs = atomicAdd(&sh_t1, (u32)__popcll(msk));
                    bs = __shfl(bs, ldr);
                    if (tie) {
                        u32 slot = bs + (u32)__popcll(msk & ((1ull << lane) - 1ull));
                        nxtb[slot] = e;
                    }
                }
            }
            __syncthreads();
            n = sh_t1;
            __syncthreads();
            u64* tmp = curb; curb = nxtb; nxtb = tmp;
        }
        u32 cs = sh_sel;
        if (n == m) {
            for (u32 j = tid; j < n; j += 1024) {
                u64 e = curb[j];
                u32 k32 = (u32)(e >> 32);
                sk[base + cs + j] = ((u64)(~k32) << 32) | (u64)(lshift | (u32)(e & 0xFFFFFFu));
            }
        } else {
            u32 kt = (u32)(curb[0] >> 32);
            u32 nc = n > 2048u ? 2048u : n;
            u32 S = 64; while (S < nc) S <<= 1;
            for (u32 j = tid; j < S; j += 1024) tiebuf[j] = 0xFFFFFFFFu;
            __syncthreads();
            for (u32 j = tid; j < nc; j += 1024) tiebuf[j] = (u32)(curb[j] & 0xFFFFFFu);
            __syncthreads();
            for (u32 ksz = 2; ksz <= S; ksz <<= 1) {
                for (u32 jj = ksz >> 1; jj > 0; jj >>= 1) {
                    for (u32 i2 = tid; i2 < S; i2 += 1024) {
                        u32 ixj = i2 ^ jj;
                        if (ixj > i2) {
                            u32 a = tiebuf[i2], b2 = tiebuf[ixj];
                            bool up = ((i2 & ksz) == 0);
                            if ((a > b2) == up) { tiebuf[i2] = b2; tiebuf[ixj] = a; }
                        }
                    }
                    __syncthreads();
                }
            }
            for (u32 j = tid; j < m; j += 1024)
                sk[base + cs + j] = ((u64)(~kt) << 32) | (u64)(lshift | tiebuf[j]);
        }
        __syncthreads();
    }
    for (int i = tid; i < 8192; i += 1024) if (i >= NCAND) sk[i] = ~0ull;
    __syncthreads();
    for (u32 ksz = 2; ksz <= 8192; ksz <<= 1) {
        for (u32 j = ksz >> 1; j > 0; j >>= 1) {
            for (u32 i = tid; i < 8192; i += 1024) {
                u32 ixj = i ^ j;
                if (ixj > i) {
                    u64 a = sk[i], b = sk[ixj];
                    bool up = ((i & ksz) == 0);
                    if ((a > b) == up) { sk[i] = b; sk[ixj] = a; }
                }
            }
            __syncthreads();
        }
    }
    const float CLAMP = 4.135166556742356f;  // log(1000/16)
    for (int s = tid; s < NCAND; s += 1024) {
        u32 info = (u32)sk[s];
        int l = info >> 24, idx = info & 0xFFFFFF;
        int W = c_W[l], st = c_stride[l];
        int a = idx % 3, pix = idx / 3;
        int x = pix % W, y = pix / W;
        float ax1 = x * st + P.b[l][a][0];
        float ay1 = y * st + P.b[l][a][1];
        float ax2 = x * st + P.b[l][a][2];
        float ay2 = y * st + P.b[l][a][3];
        float w_ = ax2 - ax1, h_ = ay2 - ay1;
        float cx = ax1 + 0.5f * w_, cy = ay1 + 0.5f * h_;
        const float* d = deltas + ((size_t)(c_soff[l] + idx)) * 4;
        float dx = d[0], dy = d[1];
        float dw = fminf(d[2], CLAMP), dh = fminf(d[3], CLAMP);
        float pcx = dx * w_ + cx, pcy = dy * h_ + cy;
        float pw = expf(dw) * w_, ph = expf(dh) * h_;
        float x1 = pcx - 0.5f * pw, y1 = pcy - 0.5f * ph;
        float x2 = pcx + 0.5f * pw, y2 = pcy + 0.5f * ph;
        x1 = fminf(fmaxf(x1, 0.f), 800.f); y1 = fminf(fmaxf(y1, 0.f), 800.f);
        x2 = fminf(fmaxf(x2, 0.f), 800.f); y2 = fminf(fmaxf(y2, 0.f), 800.f);
        u32 vv = (x2 - x1 >= 0.001f && y2 - y1 >= 0.001f) ? 1u : 0u;
        float offv = (float)l * 801.0f;
        sboxes[s * 4 + 0] = x1; sboxes[s * 4 + 1] = y1;
        sboxes[s * 4 + 2] = x2; sboxes[s * 4 + 3] = y2;
        sob[s * 4 + 0] = x1 + offv; sob[s * 4 + 1] = y1 + offv;
        sob[s * 4 + 2] = x2 + offv; sob[s * 4 + 3] = y2 + offv;
        svalid[s] = vv;
    }
}

// ---------------- kernel 4: IoU bitmask + last-block NMS scan + gather (r16, unchanged) ----------------
__global__ __launch_bounds__(1024) void k_maskscan(
    const float* __restrict__ sob, u64* __restrict__ mask,
    const u32* __restrict__ svalid, const float* __restrict__ sboxes,
    float* __restrict__ out, u32* __restrict__ cnts) {
    __shared__ u64 stage[2][64][WORDS];   // 72704 B
    __shared__ u64 keep[WORDS];
    __shared__ u32 ormL[WORDS], ormH[WORDS];
    __shared__ u32 sc[1024];
    __shared__ u32 sh_last;
    const int tid = threadIdx.x;
    int gid = blockIdx.x * 1024 + tid;
    const int total = NCAND * WORDS;
    if (gid < total) {
        int i = gid / WORDS, w = gid - i * WORDS;
        float bx1 = sob[i * 4], by1 = sob[i * 4 + 1], bx2 = sob[i * 4 + 2], by2 = sob[i * 4 + 3];
        float ai = (bx2 - bx1) * (by2 - by1);
        u64 bits = 0;
        int j0 = w * 64;
        for (int b = 0; b < 64; b++) {
            int j = j0 + b;
            if (j < NCAND && j > i) {
                float cx1 = sob[j * 4], cy1 = sob[j * 4 + 1], cx2 = sob[j * 4 + 2], cy2 = sob[j * 4 + 3];
                float lt0 = fmaxf(bx1, cx1), lt1 = fmaxf(by1, cy1);
                float rb0 = fminf(bx2, cx2), rb1 = fminf(by2, cy2);
                float ww = fmaxf(rb0 - lt0, 0.f), hh = fmaxf(rb1 - lt1, 0.f);
                float inter = ww * hh;
                float aj = (cx2 - cx1) * (cy2 - cy1);
                float u = ai + aj - inter;
                float iou = inter / u;       // 0/0 -> NaN -> no suppression (matches ref)
                if (iou > 0.7f) bits |= (1ull << b);
            }
        }
        mask[(size_t)i * WORDS + w] = bits;
    }
    __threadfence();
    if (tid == 0) sh_last = (atomicAdd(&cnts[13], 1u) == gridDim.x - 1) ? 1u : 0u;
    __syncthreads();
    if (!sh_last) return;
    __threadfence();

    if (tid < WORDS) {
        u64 w0 = 0;
        for (int b = 0; b < 64; b++) {
            int idx = tid * 64 + b;
            if (idx < NCAND && svalid[idx]) w0 |= (1ull << b);
        }
        keep[tid] = w0; ormL[tid] = 0; ormH[tid] = 0;
    }
    {
        u64* s0 = &stage[0][0][0];
        for (int e = tid; e < 64 * WORDS; e += 1024) {
            int r = e / WORDS, w = e - r * WORDS;
            s0[e] = (r < NCAND) ? mask[(size_t)r * WORDS + w] : 0ull;
        }
    }
    __syncthreads();

    for (int t = 0; t < WORDS; t++) {
        const int cur = t & 1;
        u64 pf[5];
        if (t < WORDS - 1) {
            int row0 = (t + 1) * 64;
#pragma unroll
            for (int q = 0; q < 5; q++) {
                int e = tid + q * 1024;
                u64 v = 0;
                if (e < 64 * WORDS) {
                    int r = e / WORDS, w = e - r * WORDS;
                    int row = row0 + r;
                    if (row < NCAND) v = mask[(size_t)row * WORDS + w];
                }
                pf[q] = v;
            }
        }
        if (tid < 64) {
            u64 d = stage[cur][tid][t];
            u64 nz = __ballot(d != 0ull);
            u64 curk = keep[t];
            u64 pending = curk & nz;
            while (pending) {
                int b = __builtin_ctzll(pending);
                pending &= pending - 1;
                u64 mb = stage[cur][b][t];
                curk &= ~mb;
                pending &= ~mb;
            }
            if (tid == 0) keep[t] = curk;
        }
        __syncthreads();
        u64 kw = keep[t];
        int nW = WORDS - 1 - t;
        for (int task = tid; task < 64 * nW; task += 1024) {
            int r = task / nW, w = t + 1 + (task - r * nW);
            if ((kw >> r) & 1ull) {
                u64 mrow = stage[cur][r][w];
                if (mrow) {
                    atomicOr(&ormL[w], (u32)mrow);
                    atomicOr(&ormH[w], (u32)(mrow >> 32));
                }
            }
        }
        __syncthreads();
        if (tid > t && tid < WORDS) {
            keep[tid] &= ~(((u64)ormH[tid] << 32) | (u64)ormL[tid]);
            ormL[tid] = 0; ormH[tid] = 0;
        }
        if (t < WORDS - 1) {
            u64* s1 = &stage[cur ^ 1][0][0];
#pragma unroll
            for (int q = 0; q < 5; q++) {
                int e = tid + q * 1024;
                if (e < 64 * WORDS) s1[e] = pf[q];
            }
        }
        __syncthreads();
    }
    const int i0 = tid * 5;
    u32 cnt = 0;
    for (int e = 0; e < 5; e++) {
        int i = i0 + e;
        if (i < NCAND) cnt += (u32)((keep[i >> 6] >> (i & 63)) & 1ull);
    }
    sc[tid] = cnt;
    __syncthreads();
    for (int off = 1; off < 1024; off <<= 1) {
        u32 v = (tid >= off) ? sc[tid - off] : 0;
        __syncthreads();
        sc[tid] += v;
        __syncthreads();
    }
    u32 incl = sc[tid];
    u32 totalk = sc[1023];
    u32 kr = incl - cnt;
    for (int e = 0; e < 5; e++) {
        int i = i0 + e;
        if (i < NCAND) {
            bool kp = (keep[i >> 6] >> (i & 63)) & 1ull;
            if (kp) {
                if (kr < 1000u) {
                    out[kr * 4 + 0] = sboxes[i * 4 + 0];
                    out[kr * 4 + 1] = sboxes[i * 4 + 1];
                    out[kr * 4 + 2] = sboxes[i * 4 + 2];
                    out[kr * 4 + 3] = sboxes[i * 4 + 3];
                }
                kr++;
            } else {
                u32 slot = totalk + (u32)i - kr;
                if (slot < 1000u) {
                    out[slot * 4 + 0] = sboxes[i * 4 + 0];
                    out[slot * 4 + 1] = sboxes[i * 4 + 1];
                    out[slot * 4 + 2] = sboxes[i * 4 + 2];
                    out[slot * 4 + 3] = sboxes[i * 4 + 3];
                }
            }
        }
    }
}

// ---------------- host ----------------
extern "C" void kernel_launch(void* const* d_in, const int* in_sizes, int n_in,
                              void* d_out, int out_size, void* d_ws, size_t ws_size,
                              hipStream_t stream) {
    (void)in_sizes; (void)n_in; (void)out_size; (void)ws_size;
    FeatPtrs fp;
    for (int i = 0; i < 5; i++) fp.p[i] = (const float*)d_in[i];
    const float* conv_w = (const float*)d_in[5];
    const float* conv_b = (const float*)d_in[6];
    const float* cls_w  = (const float*)d_in[7];
    const float* cls_b  = (const float*)d_in[8];
    const float* bbox_w = (const float*)d_in[9];
    const float* bbox_b = (const float*)d_in[10];

    char* ws = (char*)d_ws;
    f16*   whi    = (f16*)(ws + OFF_WHI);
    f16*   wlo    = (f16*)(ws + OFF_WLO);
    float* headw  = (float*)(ws + OFF_HEADW);
    float* headb  = (float*)(ws + OFF_HEADB);
    float* scores = (float*)(ws + OFF_SCORES);
    float* deltas = (float*)(ws + OFF_DELTAS);
    float* sboxes = (float*)(ws + OFF_SBOX);
    float* sob    = (float*)(ws + OFF_SOB);
    u32*   svalid = (u32*)(ws + OFF_SVAL);
    u64*   maskp  = (u64*)(ws + OFF_MASK);
    u32*   ghist  = (u32*)(ws + OFF_GHIST);
    u32*   cnts   = (u32*)(ws + OFF_CNT);
    u64*   key    = (u64*)(ws + OFF_KEY);
    u64*   scr1   = maskp;          // tie scratch (free before mask phase)
    u64*   scr2   = maskp + TOTS;

    k_prep<<<2304, 256, 0, stream>>>(conv_w, cls_w, cls_b, bbox_w, bbox_b,
                                     whi, wlo, headw, headb, ghist, cnts);

    k_conv<<<CONVGRID, 512, 0, stream>>>(fp, whi, wlo, conv_b, headw, headb,
                                         scores, deltas, ghist);

    DecParams dp;
    {
        const double sz[5] = {32.0, 64.0, 128.0, 256.0, 512.0};
        const double rt[3] = {0.5, 1.0, 2.0};
        for (int l = 0; l < 5; l++)
            for (int a = 0; a < 3; a++) {
                double hr = sqrt(rt[a]);
                double wr = 1.0 / hr;
                double w = wr * sz[l], h = hr * sz[l];
                dp.b[l][a][0] = (float)nearbyint(-w / 2.0);
                dp.b[l][a][1] = (float)nearbyint(-h / 2.0);
                dp.b[l][a][2] = (float)nearbyint(w / 2.0);
                dp.b[l][a][3] = (float)nearbyint(h / 2.0);
            }
    }
    k_clsfin<<<128, 1024, 0, stream>>>(scores, ghist, key, scr1, scr2, cnts,
                                       deltas, dp, sboxes, sob, svalid);
    k_maskscan<<<(NCAND * WORDS + 1023) / 1024, 1024, 0, stream>>>(
        sob, maskp, svalid, sboxes, (float*)d_out, cnts);
}

// Round 20
// 819.273 us; speedup vs baseline: 1.0882x; 1.0882x over previous
//
#include <hip/hip_runtime.h>
#include <cmath>

typedef unsigned int u32;
typedef unsigned long long u64;
typedef _Float16 f16;
typedef _Float16 f16x8 __attribute__((ext_vector_type(8)));
typedef float f32x4 __attribute__((ext_vector_type(4)));

// address-space-qualified typedefs for global_load_lds
typedef __attribute__((address_space(1))) const unsigned int gu32;
typedef __attribute__((address_space(3))) unsigned int lu32;

#define NCAND 4507
#define WORDS 71              // ceil(4507/64)
#define ROWS_AL (WORDS * 64)  // 4544
#define TOTS 159882           // total scores across levels
#define NTILES 863
#define CONVGRID 512

__constant__ int c_W[5]      = {200, 100, 50, 25, 13};
__constant__ int c_stride[5] = {4, 8, 16, 32, 61};
__constant__ int c_Nl[5]     = {120000, 30000, 7500, 1875, 507};
__constant__ int c_soff[5]   = {0, 120000, 150000, 157500, 159375};
__constant__ int c_k[5]      = {1000, 1000, 1000, 1000, 507};

// unified conv grid: tiles per level (8x8 px tiles): 625,169,49,16,4
__constant__ int cv_boff[6]  = {0, 625, 794, 843, 859, 863};

struct DecParams { float b[5][3][4]; };
struct FeatPtrs { const float* p[5]; };

__device__ __forceinline__ u32 flipf(float f) {
    u32 u = __float_as_uint(f);
    return (u & 0x80000000u) ? ~u : (u | 0x80000000u);
}

// ---------------- workspace layout ----------------
constexpr size_t AL(size_t x) { return (x + 255) & ~(size_t)255; }
constexpr size_t OFF_WHI    = 0;                                   // 589824 f16
constexpr size_t OFF_WLO    = AL(OFF_WHI + 1179648);               // 589824 f16
constexpr size_t OFF_HEADW  = AL(OFF_WLO + 1179648);               // 15*256 f
constexpr size_t OFF_HEADB  = AL(OFF_HEADW + 3840 * 4);            // 15 f
constexpr size_t OFF_SCORES = AL(OFF_HEADB + 64);                  // TOTS f
constexpr size_t OFF_DELTAS = AL(OFF_SCORES + (size_t)TOTS * 4);   // TOTS*4 f
constexpr size_t OFF_SBOX   = AL(OFF_DELTAS + (size_t)TOTS * 16);  // NCAND*4 f
constexpr size_t OFF_SOB    = AL(OFF_SBOX + (size_t)NCAND * 16);   // NCAND*4 f
constexpr size_t OFF_SVAL   = AL(OFF_SOB + (size_t)NCAND * 16);    // NCAND u32
constexpr size_t OFF_MASK   = AL(OFF_SVAL + (size_t)NCAND * 4);    // ROWS_AL*WORDS u64 (2.58 MB)
constexpr size_t OFF_KEEP   = AL(OFF_MASK + (size_t)ROWS_AL * WORDS * 8); // WORDS u64
constexpr size_t OFF_GHIST  = AL(OFF_KEEP + WORDS * 8);            // 5*256 u32
constexpr size_t OFF_CNT    = AL(OFF_GHIST + 1280 * 4);            // 16 u32 (sel 0..4, tie 8..11, done 12/13)
constexpr size_t OFF_KEY    = AL(OFF_CNT + 64);                    // 5000 u64
// classify/finish use the MASK region as tie scratch (2x TOTS u64 <= 2.58 MB);
// safe: mask phase fully rewrites MASK afterwards (separate dispatch).

// ---------------- kernel 1: weight prep (OUTPUT-LINEAR, coalesced) + state zeroing ----------------
__global__ __launch_bounds__(256) void k_prep(
    const float* __restrict__ cw, const float* __restrict__ clsw,
    const float* __restrict__ clsb, const float* __restrict__ bw,
    const float* __restrict__ bb, f16* __restrict__ whi, f16* __restrict__ wlo,
    float* __restrict__ headw, float* __restrict__ headb,
    u32* __restrict__ ghist, u32* __restrict__ cnts) {
    int i = blockIdx.x * 256 + threadIdx.x;
    if (i < 589824) {
        int blk = i >> 13;          // 72 blocks of 8192 f16
        int within = i & 8191;
        int co = within >> 5;
        int rem = within & 31;
        int slot = rem >> 3, j = rem & 7;
        int chunk = blk / 9, kk = blk - chunk * 9;
        int ky = kk / 3, kx = kk - ky * 3;
        int g = slot ^ ((co >> 1) & 3);
        int ci = (chunk << 5) | (g << 3) | j;
        float w = cw[(((co << 8) + ci) * 3 + ky) * 3 + kx];
        f16 hi = (f16)w;
        whi[i] = hi;
        wlo[i] = (f16)((w - (float)hi) * 2048.0f);
    }
    if (i < 3840) {
        int h = i >> 8, ci = i & 255;
        headw[i] = (h < 3) ? clsw[h * 256 + ci] : bw[(h - 3) * 256 + ci];
    }
    if (i < 15) headb[i] = (i < 3) ? clsb[i] : bb[i - 3];
    if (i < 1280) ghist[i] = 0;
    if (i < 16) cnts[i] = 0;
}

// ---------------- kernel 2: MFMA fp16-split conv + heads + fused score hist ----------------
// R16-EXACT (final). Conv-structure ledger (4-way verified local optimum):
//   r16: LDS dbuf B via global_load_lds, per-step barrier -> 408 us  <- best
//   r5:  reg prefetch             -> VGPR 164, occupancy halved, regressed
//   r6:  gload_lds single-buffer  -> VGPR 152, regressed
//   r17: B direct-from-L2, no LDS -> pipeline lost, 444 us
//   r19: hybrid (hi LDS, lo L2)   -> VGPR-bound at 2/CU + exposed lo loads, 467 us
__global__ __launch_bounds__(512) void k_conv(
    FeatPtrs fp, const f16* __restrict__ whi, const f16* __restrict__ wlo,
    const float* __restrict__ convb, const float* __restrict__ headw,
    const float* __restrict__ headb, float* __restrict__ scores,
    float* __restrict__ deltas, u32* __restrict__ ghist) {
    __shared__ float4 smq[4896];  // 78336 B: A hi/lo 2x6400 @0, B 2x32768 @12800
    char* smb = (char*)smq;
    const int tid = threadIdx.x;
    const int lane = tid & 63, wv = tid >> 6;
    const int l15 = lane & 15, l4 = lane >> 4;

    int rbase0, rbase1, rbase2, rbase3;
    {
        int rr = l15 >> 3;
        rbase0 = (0 + rr) * 640; rbase1 = (2 + rr) * 640;
        rbase2 = (4 + rr) * 640; rbase3 = (6 + rr) * 640;
    }
    int colx0, colx1, colx2;
    {
        int c = lane & 7;
        int p0 = c, p1 = c + 1, p2 = c + 2;
        colx0 = p0 * 64 + ((l4 ^ ((p0 >> 1) & 3)) << 4);
        colx1 = p1 * 64 + ((l4 ^ ((p1 >> 1) & 3)) << 4);
        colx2 = p2 * 64 + ((l4 ^ ((p2 >> 1) & 3)) << 4);
    }
    const int bco0 = wv * 32 + l15, bco1 = wv * 32 + 16 + l15;
    const int boff0 = bco0 * 64 + ((l4 ^ ((bco0 >> 1) & 3)) << 4);
    const int boff1 = bco1 * 64 + ((l4 ^ ((bco1 >> 1) & 3)) << 4);

    for (int bt = blockIdx.x; bt < NTILES; bt += gridDim.x) {
        int l = 0;
#pragma unroll
        for (int q = 1; q < 5; q++) if (bt >= cv_boff[q]) l = q;
        const int H = c_W[l], W = H;
        const int soff = c_soff[l];
        const float* __restrict__ in = fp.p[l];
        const int t = bt - cv_boff[l];
        const int tilesx = (W + 7) >> 3;
        const int tx = t % tilesx, ty = t / tilesx;
        const int x0 = tx * 8, y0 = ty * 8;
        const int HW = H * W;

        f32x4 acc1[4][2], acc2[4][2];
#pragma unroll
        for (int mt = 0; mt < 4; mt++)
#pragma unroll
            for (int nt = 0; nt < 2; nt++) {
                acc1[mt][nt] = (f32x4)0.0f;
                acc2[mt][nt] = (f32x4)0.0f;
            }

        auto stagePatch = [&](int chunk) {
            const int c0 = chunk << 5;
            f16* ph = (f16*)smb;
            f16* pl = (f16*)(smb + 6400);
            for (int e = tid; e < 3200; e += 512) {
                int py = e / 320, rem = e - py * 320;
                int px = rem >> 5, ci = rem & 31;
                int gy = y0 - 1 + py, gx = x0 - 1 + px;
                float v = 0.f;
                if (gy >= 0 && gy < H && gx >= 0 && gx < W)
                    v = in[(c0 + ci) * HW + gy * W + gx];
                f16 hi = (f16)v;
                int widx = py * 320 + px * 32 + (((ci >> 3) ^ ((px >> 1) & 3)) << 3) + (ci & 7);
                ph[widx] = hi;
                pl[widx] = (f16)((v - (float)hi) * 2048.0f);
            }
        };
        auto issueB = [&](int sidx, int buf) {
            const char* gh = (const char*)whi + (size_t)sidx * 16384;
            const char* gl = (const char*)wlo + (size_t)sidx * 16384;
            char* dh = smb + 12800 + buf * 32768;
            char* dl = dh + 16384;
#pragma unroll
            for (int q = 0; q < 2; q++) {
                int i1 = (wv * 2 + q) * 1024;
                __builtin_amdgcn_global_load_lds((gu32*)(gh + i1 + lane * 16), (lu32*)(dh + i1), 16, 0, 0);
                __builtin_amdgcn_global_load_lds((gu32*)(gl + i1 + lane * 16), (lu32*)(dl + i1), 16, 0, 0);
            }
        };

        stagePatch(0);
        issueB(0, 0);
        __syncthreads();

        for (int chunk = 0; chunk < 8; ++chunk) {
            if (chunk) { stagePatch(chunk); __syncthreads(); }
#pragma unroll
            for (int kk = 0; kk < 9; ++kk) {
                const int s = chunk * 9 + kk;
                const int buf = s & 1;
                if (s < 71) issueB(s + 1, buf ^ 1);
                {
                    const int ky = kk / 3, kx = kk - ky * 3;
                    const int kyb = ky * 640;
                    const int cx = (kx == 0) ? colx0 : (kx == 1) ? colx1 : colx2;
                    const char* bh = smb + 12800 + buf * 32768;
                    const char* bl = bh + 16384;
                    f16x8 ah0 = *(const f16x8*)(smb + rbase0 + kyb + cx);
                    f16x8 ah1 = *(const f16x8*)(smb + rbase1 + kyb + cx);
                    f16x8 ah2 = *(const f16x8*)(smb + rbase2 + kyb + cx);
                    f16x8 ah3 = *(const f16x8*)(smb + rbase3 + kyb + cx);
                    f16x8 al0 = *(const f16x8*)(smb + 6400 + rbase0 + kyb + cx);
                    f16x8 al1 = *(const f16x8*)(smb + 6400 + rbase1 + kyb + cx);
                    f16x8 al2 = *(const f16x8*)(smb + 6400 + rbase2 + kyb + cx);
                    f16x8 al3 = *(const f16x8*)(smb + 6400 + rbase3 + kyb + cx);
#pragma unroll
                    for (int nt = 0; nt < 2; nt++) {
                        const int bo = nt ? boff1 : boff0;
                        f16x8 vbh = *(const f16x8*)(bh + bo);
                        f16x8 vbl = *(const f16x8*)(bl + bo);
                        acc1[0][nt] = __builtin_amdgcn_mfma_f32_16x16x32_f16(ah0, vbh, acc1[0][nt], 0, 0, 0);
                        acc2[0][nt] = __builtin_amdgcn_mfma_f32_16x16x32_f16(ah0, vbl, acc2[0][nt], 0, 0, 0);
                        acc2[0][nt] = __builtin_amdgcn_mfma_f32_16x16x32_f16(al0, vbh, acc2[0][nt], 0, 0, 0);
                        acc1[1][nt] = __builtin_amdgcn_mfma_f32_16x16x32_f16(ah1, vbh, acc1[1][nt], 0, 0, 0);
                        acc2[1][nt] = __builtin_amdgcn_mfma_f32_16x16x32_f16(ah1, vbl, acc2[1][nt], 0, 0, 0);
                        acc2[1][nt] = __builtin_amdgcn_mfma_f32_16x16x32_f16(al1, vbh, acc2[1][nt], 0, 0, 0);
                        acc1[2][nt] = __builtin_amdgcn_mfma_f32_16x16x32_f16(ah2, vbh, acc1[2][nt], 0, 0, 0);
                        acc2[2][nt] = __builtin_amdgcn_mfma_f32_16x16x32_f16(ah2, vbl, acc2[2][nt], 0, 0, 0);
                        acc2[2][nt] = __builtin_amdgcn_mfma_f32_16x16x32_f16(al2, vbh, acc2[2][nt], 0, 0, 0);
                        acc1[3][nt] = __builtin_amdgcn_mfma_f32_16x16x32_f16(ah3, vbh, acc1[3][nt], 0, 0, 0);
                        acc2[3][nt] = __builtin_amdgcn_mfma_f32_16x16x32_f16(ah3, vbl, acc2[3][nt], 0, 0, 0);
                        acc2[3][nt] = __builtin_amdgcn_mfma_f32_16x16x32_f16(al3, vbh, acc2[3][nt], 0, 0, 0);
                    }
                }
                __syncthreads();
            }
        }

        const float INV2048 = 4.8828125e-4f;
        {
            float cb0 = convb[bco0], cb1 = convb[bco1];
#pragma unroll
            for (int mt = 0; mt < 4; mt++)
#pragma unroll
                for (int nt = 0; nt < 2; nt++) {
                    float cb = nt ? cb1 : cb0;
#pragma unroll
                    for (int r = 0; r < 4; r++) {
                        float tv = acc1[mt][nt][r] + acc2[mt][nt][r] * INV2048 + cb;
                        acc1[mt][nt][r] = tv > 0.f ? tv : 0.f;
                    }
                }
        }

        u32* lhist = (u32*)(smb + 12800);
        for (int i = tid; i < 1280; i += 512) lhist[i] = 0;

        float* part = (float*)smb;  // [8 wv][64 px][3]
        for (int hc = 0; hc < 15; hc += 3) {
            float hw3[3][2];
#pragma unroll
            for (int h3 = 0; h3 < 3; h3++) {
                hw3[h3][0] = headw[(hc + h3) * 256 + bco0];
                hw3[h3][1] = headw[(hc + h3) * 256 + bco1];
            }
#pragma unroll
            for (int mt = 0; mt < 4; mt++)
#pragma unroll
                for (int r = 0; r < 4; r++) {
                    float p0 = 0.f, p1 = 0.f, p2 = 0.f;
#pragma unroll
                    for (int nt = 0; nt < 2; nt++) {
                        float tv = acc1[mt][nt][r];
                        p0 = fmaf(hw3[0][nt], tv, p0);
                        p1 = fmaf(hw3[1][nt], tv, p1);
                        p2 = fmaf(hw3[2][nt], tv, p2);
                    }
                    p0 += __shfl_xor(p0, 1); p0 += __shfl_xor(p0, 2); p0 += __shfl_xor(p0, 4); p0 += __shfl_xor(p0, 8);
                    p1 += __shfl_xor(p1, 1); p1 += __shfl_xor(p1, 2); p1 += __shfl_xor(p1, 4); p1 += __shfl_xor(p1, 8);
                    p2 += __shfl_xor(p2, 1); p2 += __shfl_xor(p2, 2); p2 += __shfl_xor(p2, 4); p2 += __shfl_xor(p2, 8);
                    if (l15 == 0) {
                        int px = mt * 16 + l4 * 4 + r;
                        part[(wv * 64 + px) * 3 + 0] = p0;
                        part[(wv * 64 + px) * 3 + 1] = p1;
                        part[(wv * 64 + px) * 3 + 2] = p2;
                    }
                }
            __syncthreads();
            if (tid < 192) {
                int px = tid / 3, h3 = tid % 3;
                int h = hc + h3;
                float sum = 0.f;
#pragma unroll
                for (int g = 0; g < 8; g++) sum += part[(g * 64 + px) * 3 + h3];
                sum += headb[h];
                int gy = y0 + (px >> 3), gx = x0 + (px & 7);
                if (gy < H && gx < W) {
                    int pix = gy * W + gx;
                    if (h < 3) {
                        scores[soff + pix * 3 + h] = sum;
                        atomicAdd(&lhist[l * 256 + (flipf(sum) >> 24)], 1u);
                    } else {
                        int ch2 = h - 3;
                        deltas[((size_t)(soff + pix * 3 + (ch2 >> 2))) * 4 + (ch2 & 3)] = sum;
                    }
                }
            }
            __syncthreads();
        }
        for (int i = tid; i < 1280; i += 512) {
            u32 v = lhist[i];
            if (v) atomicAdd(&ghist[i], v);
        }
        __syncthreads();
    }
}

// ---------------- kernel 3: classify (chip-parallel) + last-block finish (r16, unchanged) ----------------
__global__ __launch_bounds__(1024) void k_clsfin(
    const float* __restrict__ scores, const u32* __restrict__ ghist,
    u64* __restrict__ key, u64* __restrict__ scr1, u64* __restrict__ scr2,
    u32* __restrict__ cnts, const float* __restrict__ deltas, DecParams P,
    float* __restrict__ sboxes, float* __restrict__ sob, u32* __restrict__ svalid) {
    __shared__ u64 sk[8192];
    __shared__ u32 lh[1280];
    __shared__ u32 tiebuf[2048];
    __shared__ u32 sb0[5];
    __shared__ u32 sh_sel, sh_t1, sh_t2, sh_m, sh_last;
    const int tid = threadIdx.x;
    const int lane = tid & 63;

    for (int i = tid; i < 1280; i += 1024) lh[i] = ghist[i];
    __syncthreads();
    if (tid < 4) {
        int l = tid;
        u32 m0 = (u32)c_k[l];
        u32 cum = 0;
        for (int b = 255; b >= 0; --b) {
            u32 c = lh[l * 256 + b];
            if (cum + c >= m0) { sb0[l] = (u32)b; break; }
            cum += c;
        }
    }
    __syncthreads();
    const int gsz = gridDim.x * 1024;
    for (int i = blockIdx.x * 1024 + tid; i < TOTS; i += gsz) {
        int l = (i >= 120000) + (i >= 150000) + (i >= 157500) + (i >= 159375);
        u32 il = (u32)(i - c_soff[l]);
        u32 k32 = flipf(scores[i]);
        u32 b = k32 >> 24;
        bool sel = (l == 4) || (b > sb0[l]);
        bool tie = (l < 4) && (b == sb0[l]);
        u64 m1 = __ballot(sel);
        while (m1) {
            int ldr = __builtin_ctzll(m1);
            int lv = __shfl(l, ldr);
            u64 grp = __ballot(sel && (l == lv));
            u32 bs = 0;
            if (lane == ldr) bs = atomicAdd(&cnts[lv], (u32)__popcll(grp));
            bs = __shfl(bs, ldr);
            if (sel && l == lv) {
                u32 slot = bs + (u32)__popcll(grp & ((1ull << lane) - 1ull));
                key[lv * 1000 + slot] = ((u64)(~k32) << 32) | (u64)(((u32)lv << 24) | il);
            }
            m1 &= ~grp;
        }
        u64 m2 = __ballot(tie);
        while (m2) {
            int ldr = __builtin_ctzll(m2);
            int lv = __shfl(l, ldr);
            u64 grp = __ballot(tie && (l == lv));
            u32 bs = 0;
            if (lane == ldr) bs = atomicAdd(&cnts[8 + lv], (u32)__popcll(grp));
            bs = __shfl(bs, ldr);
            if (tie && l == lv) {
                u32 slot = bs + (u32)__popcll(grp & ((1ull << lane) - 1ull));
                scr1[c_soff[lv] + slot] = ((u64)k32 << 32) | (u64)il;
            }
            m2 &= ~grp;
        }
    }
    __threadfence();
    if (tid == 0) sh_last = (atomicAdd(&cnts[12], 1u) == gridDim.x - 1) ? 1u : 0u;
    __syncthreads();
    if (!sh_last) return;
    __threadfence();

    u32* hist = lh;
    for (int l = 0; l < 5; ++l) {
        u32 n = cnts[l];
        int base = l * 1000;
        for (u32 j = tid; j < n; j += 1024) sk[base + j] = key[base + j];
    }
    __syncthreads();
    for (int l = 0; l < 4; ++l) {
        const int off = c_soff[l], base = l * 1000;
        const u32 lshift = (u32)l << 24;
        u32 nsel = cnts[l];
        u32 m = (u32)c_k[l] - nsel;
        u32 n = cnts[8 + l];
        u64* curb = scr1 + off;
        u64* nxtb = scr2 + off;
        if (tid == 0) sh_sel = nsel;
        __syncthreads();
        for (int p = 1; p <= 3; ++p) {
            if (n == m) break;
            const int shift = 56 - 8 * p;
            for (int b = tid; b < 256; b += 1024) hist[b] = 0;
            if (tid == 0) sh_t1 = 0;
            __syncthreads();
            for (u32 j = tid; j < n; j += 1024)
                atomicAdd(&hist[(u32)(curb[j] >> shift) & 255u], 1u);
            __syncthreads();
            if (tid == 0) {
                u32 cum = 0;
                for (int b = 255; b >= 0; --b) {
                    u32 c = hist[b];
                    if (cum + c >= m) { sh_t2 = (u32)b; sh_m = m - cum; break; }
                    cum += c;
                }
            }
            __syncthreads();
            u32 bp = sh_t2; m = sh_m;
            for (u32 j = tid; j < n; j += 1024) {
                u64 e = curb[j];
                u32 b = (u32)(e >> shift) & 255u;
                bool sel = b > bp, tie = (b == bp);
                u64 msk = __ballot(sel);
                if (msk) {
                    int ldr = __builtin_ctzll(msk);
                    u32 bs = 0;
                    if (lane == ldr) bs = atomicAdd(&sh_sel, (u32)__popcll(msk));
                    bs = __shfl(bs, ldr);
                    if (sel) {
                        u32 slot = bs + (u32)__popcll(msk & ((1ull << lane) - 1ull));
                        u32 k32 = (u32)(e >> 32);
                        sk[base + slot] = ((u64)(~k32) << 32) | (u64)(lshift | (u32)(e & 0xFFFFFFu));
                    }
                }
                msk = __ballot(tie);
                if (msk) {
                    int ldr = __builtin_ctzll(msk);
                    u32 bs = 0;
                    if (lane == ldr) bs = atomicAdd(&sh_t1, (u32)__popcll(msk));
                    bs = __shfl(bs, ldr);
                    if (tie) {
                        u32 slot = bs + (u32)__popcll(msk & ((1ull << lane) - 1ull));
                        nxtb[slot] = e;
                    }
                }
            }
            __syncthreads();
            n = sh_t1;
            __syncthreads();
            u64* tmp = curb; curb = nxtb; nxtb = tmp;
        }
        u32 cs = sh_sel;
        if (n == m) {
            for (u32 j = tid; j < n; j += 1024) {
                u64 e = curb[j];
                u32 k32 = (u32)(e >> 32);
                sk[base + cs + j] = ((u64)(~k32) << 32) | (u64)(lshift | (u32)(e & 0xFFFFFFu));
            }
        } else {
            u32 kt = (u32)(curb[0] >> 32);
            u32 nc = n > 2048u ? 2048u : n;
            u32 S = 64; while (S < nc) S <<= 1;
            for (u32 j = tid; j < S; j += 1024) tiebuf[j] = 0xFFFFFFFFu;
            __syncthreads();
            for (u32 j = tid; j < nc; j += 1024) tiebuf[j] = (u32)(curb[j] & 0xFFFFFFu);
            __syncthreads();
            for (u32 ksz = 2; ksz <= S; ksz <<= 1) {
                for (u32 jj = ksz >> 1; jj > 0; jj >>= 1) {
                    for (u32 i2 = tid; i2 < S; i2 += 1024) {
                        u32 ixj = i2 ^ jj;
                        if (ixj > i2) {
                            u32 a = tiebuf[i2], b2 = tiebuf[ixj];
                            bool up = ((i2 & ksz) == 0);
                            if ((a > b2) == up) { tiebuf[i2] = b2; tiebuf[ixj] = a; }
                        }
                    }
                    __syncthreads();
                }
            }
            for (u32 j = tid; j < m; j += 1024)
                sk[base + cs + j] = ((u64)(~kt) << 32) | (u64)(lshift | tiebuf[j]);
        }
        __syncthreads();
    }
    for (int i = tid; i < 8192; i += 1024) if (i >= NCAND) sk[i] = ~0ull;
    __syncthreads();
    for (u32 ksz = 2; ksz <= 8192; ksz <<= 1) {
        for (u32 j = ksz >> 1; j > 0; j >>= 1) {
            for (u32 i = tid; i < 8192; i += 1024) {
                u32 ixj = i ^ j;
                if (ixj > i) {
                    u64 a = sk[i], b = sk[ixj];
                    bool up = ((i & ksz) == 0);
                    if ((a > b) == up) { sk[i] = b; sk[ixj] = a; }
                }
            }
            __syncthreads();
        }
    }
    const float CLAMP = 4.135166556742356f;  // log(1000/16)
    for (int s = tid; s < NCAND; s += 1024) {
        u32 info = (u32)sk[s];
        int l = info >> 24, idx = info & 0xFFFFFF;
        int W = c_W[l], st = c_stride[l];
        int a = idx % 3, pix = idx / 3;
        int x = pix % W, y = pix / W;
        float ax1 = x * st + P.b[l][a][0];
        float ay1 = y * st + P.b[l][a][1];
        float ax2 = x * st + P.b[l][a][2];
        float ay2 = y * st + P.b[l][a][3];
        float w_ = ax2 - ax1, h_ = ay2 - ay1;
        float cx = ax1 + 0.5f * w_, cy = ay1 + 0.5f * h_;
        const float* d = deltas + ((size_t)(c_soff[l] + idx)) * 4;
        float dx = d[0], dy = d[1];
        float dw = fminf(d[2], CLAMP), dh = fminf(d[3], CLAMP);
        float pcx = dx * w_ + cx, pcy = dy * h_ + cy;
        float pw = expf(dw) * w_, ph = expf(dh) * h_;
        float x1 = pcx - 0.5f * pw, y1 = pcy - 0.5f * ph;
        float x2 = pcx + 0.5f * pw, y2 = pcy + 0.5f * ph;
        x1 = fminf(fmaxf(x1, 0.f), 800.f); y1 = fminf(fmaxf(y1, 0.f), 800.f);
        x2 = fminf(fmaxf(x2, 0.f), 800.f); y2 = fminf(fmaxf(y2, 0.f), 800.f);
        u32 vv = (x2 - x1 >= 0.001f && y2 - y1 >= 0.001f) ? 1u : 0u;
        float offv = (float)l * 801.0f;
        sboxes[s * 4 + 0] = x1; sboxes[s * 4 + 1] = y1;
        sboxes[s * 4 + 2] = x2; sboxes[s * 4 + 3] = y2;
        sob[s * 4 + 0] = x1 + offv; sob[s * 4 + 1] = y1 + offv;
        sob[s * 4 + 2] = x2 + offv; sob[s * 4 + 3] = y2 + offv;
        svalid[s] = vv;
    }
}

// ---------------- kernel 4: IoU bitmask + last-block NMS scan + gather (r16, unchanged) ----------------
__global__ __launch_bounds__(1024) void k_maskscan(
    const float* __restrict__ sob, u64* __restrict__ mask,
    const u32* __restrict__ svalid, const float* __restrict__ sboxes,
    float* __restrict__ out, u32* __restrict__ cnts) {
    __shared__ u64 stage[2][64][WORDS];   // 72704 B
    __shared__ u64 keep[WORDS];
    __shared__ u32 ormL[WORDS], ormH[WORDS];
    __shared__ u32 sc[1024];
    __shared__ u32 sh_last;
    const int tid = threadIdx.x;
    int gid = blockIdx.x * 1024 + tid;
    const int total = NCAND * WORDS;
    if (gid < total) {
        int i = gid / WORDS, w = gid - i * WORDS;
        float bx1 = sob[i * 4], by1 = sob[i * 4 + 1], bx2 = sob[i * 4 + 2], by2 = sob[i * 4 + 3];
        float ai = (bx2 - bx1) * (by2 - by1);
        u64 bits = 0;
        int j0 = w * 64;
        for (int b = 0; b < 64; b++) {
            int j = j0 + b;
            if (j < NCAND && j > i) {
                float cx1 = sob[j * 4], cy1 = sob[j * 4 + 1], cx2 = sob[j * 4 + 2], cy2 = sob[j * 4 + 3];
                float lt0 = fmaxf(bx1, cx1), lt1 = fmaxf(by1, cy1);
                float rb0 = fminf(bx2, cx2), rb1 = fminf(by2, cy2);
                float ww = fmaxf(rb0 - lt0, 0.f), hh = fmaxf(rb1 - lt1, 0.f);
                float inter = ww * hh;
                float aj = (cx2 - cx1) * (cy2 - cy1);
                float u = ai + aj - inter;
                float iou = inter / u;       // 0/0 -> NaN -> no suppression (matches ref)
                if (iou > 0.7f) bits |= (1ull << b);
            }
        }
        mask[(size_t)i * WORDS + w] = bits;
    }
    __threadfence();
    if (tid == 0) sh_last = (atomicAdd(&cnts[13], 1u) == gridDim.x - 1) ? 1u : 0u;
    __syncthreads();
    if (!sh_last) return;
    __threadfence();

    if (tid < WORDS) {
        u64 w0 = 0;
        for (int b = 0; b < 64; b++) {
            int idx = tid * 64 + b;
            if (idx < NCAND && svalid[idx]) w0 |= (1ull << b);
        }
        keep[tid] = w0; ormL[tid] = 0; ormH[tid] = 0;
    }
    {
        u64* s0 = &stage[0][0][0];
        for (int e = tid; e < 64 * WORDS; e += 1024) {
            int r = e / WORDS, w = e - r * WORDS;
            s0[e] = (r < NCAND) ? mask[(size_t)r * WORDS + w] : 0ull;
        }
    }
    __syncthreads();

    for (int t = 0; t < WORDS; t++) {
        const int cur = t & 1;
        u64 pf[5];
        if (t < WORDS - 1) {
            int row0 = (t + 1) * 64;
#pragma unroll
            for (int q = 0; q < 5; q++) {
                int e = tid + q * 1024;
                u64 v = 0;
                if (e < 64 * WORDS) {
                    int r = e / WORDS, w = e - r * WORDS;
                    int row = row0 + r;
                    if (row < NCAND) v = mask[(size_t)row * WORDS + w];
                }
                pf[q] = v;
            }
        }
        if (tid < 64) {
            u64 d = stage[cur][tid][t];
            u64 nz = __ballot(d != 0ull);
            u64 curk = keep[t];
            u64 pending = curk & nz;
            while (pending) {
                int b = __builtin_ctzll(pending);
                pending &= pending - 1;
                u64 mb = stage[cur][b][t];
                curk &= ~mb;
                pending &= ~mb;
            }
            if (tid == 0) keep[t] = curk;
        }
        __syncthreads();
        u64 kw = keep[t];
        int nW = WORDS - 1 - t;
        for (int task = tid; task < 64 * nW; task += 1024) {
            int r = task / nW, w = t + 1 + (task - r * nW);
            if ((kw >> r) & 1ull) {
                u64 mrow = stage[cur][r][w];
                if (mrow) {
                    atomicOr(&ormL[w], (u32)mrow);
                    atomicOr(&ormH[w], (u32)(mrow >> 32));
                }
            }
        }
        __syncthreads();
        if (tid > t && tid < WORDS) {
            keep[tid] &= ~(((u64)ormH[tid] << 32) | (u64)ormL[tid]);
            ormL[tid] = 0; ormH[tid] = 0;
        }
        if (t < WORDS - 1) {
            u64* s1 = &stage[cur ^ 1][0][0];
#pragma unroll
            for (int q = 0; q < 5; q++) {
                int e = tid + q * 1024;
                if (e < 64 * WORDS) s1[e] = pf[q];
            }
        }
        __syncthreads();
    }
    const int i0 = tid * 5;
    u32 cnt = 0;
    for (int e = 0; e < 5; e++) {
        int i = i0 + e;
        if (i < NCAND) cnt += (u32)((keep[i >> 6] >> (i & 63)) & 1ull);
    }
    sc[tid] = cnt;
    __syncthreads();
    for (int off = 1; off < 1024; off <<= 1) {
        u32 v = (tid >= off) ? sc[tid - off] : 0;
        __syncthreads();
        sc[tid] += v;
        __syncthreads();
    }
    u32 incl = sc[tid];
    u32 totalk = sc[1023];
    u32 kr = incl - cnt;
    for (int e = 0; e < 5; e++) {
        int i = i0 + e;
        if (i < NCAND) {
            bool kp = (keep[i >> 6] >> (i & 63)) & 1ull;
            if (kp) {
                if (kr < 1000u) {
                    out[kr * 4 + 0] = sboxes[i * 4 + 0];
                    out[kr * 4 + 1] = sboxes[i * 4 + 1];
                    out[kr * 4 + 2] = sboxes[i * 4 + 2];
                    out[kr * 4 + 3] = sboxes[i * 4 + 3];
                }
                kr++;
            } else {
                u32 slot = totalk + (u32)i - kr;
                if (slot < 1000u) {
                    out[slot * 4 + 0] = sboxes[i * 4 + 0];
                    out[slot * 4 + 1] = sboxes[i * 4 + 1];
                    out[slot * 4 + 2] = sboxes[i * 4 + 2];
                    out[slot * 4 + 3] = sboxes[i * 4 + 3];
                }
            }
        }
    }
}

// ---------------- host ----------------
extern "C" void kernel_launch(void* const* d_in, const int* in_sizes, int n_in,
                              void* d_out, int out_size, void* d_ws, size_t ws_size,
                              hipStream_t stream) {
    (void)in_sizes; (void)n_in; (void)out_size; (void)ws_size;
    FeatPtrs fp;
    for (int i = 0; i < 5; i++) fp.p[i] = (const float*)d_in[i];
    const float* conv_w = (const float*)d_in[5];
    const float* conv_b = (const float*)d_in[6];
    const float* cls_w  = (const float*)d_in[7];
    const float* cls_b  = (const float*)d_in[8];
    const float* bbox_w = (const float*)d_in[9];
    const float* bbox_b = (const float*)d_in[10];

    char* ws = (char*)d_ws;
    f16*   whi    = (f16*)(ws + OFF_WHI);
    f16*   wlo    = (f16*)(ws + OFF_WLO);
    float* headw  = (float*)(ws + OFF_HEADW);
    float* headb  = (float*)(ws + OFF_HEADB);
    float* scores = (float*)(ws + OFF_SCORES);
    float* deltas = (float*)(ws + OFF_DELTAS);
    float* sboxes = (float*)(ws + OFF_SBOX);
    float* sob    = (float*)(ws + OFF_SOB);
    u32*   svalid = (u32*)(ws + OFF_SVAL);
    u64*   maskp  = (u64*)(ws + OFF_MASK);
    u32*   ghist  = (u32*)(ws + OFF_GHIST);
    u32*   cnts   = (u32*)(ws + OFF_CNT);
    u64*   key    = (u64*)(ws + OFF_KEY);
    u64*   scr1   = maskp;          // tie scratch (free before mask phase)
    u64*   scr2   = maskp + TOTS;

    k_prep<<<2304, 256, 0, stream>>>(conv_w, cls_w, cls_b, bbox_w, bbox_b,
                                     whi, wlo, headw, headb, ghist, cnts);

    k_conv<<<CONVGRID, 512, 0, stream>>>(fp, whi, wlo, conv_b, headw, headb,
                                         scores, deltas, ghist);

    DecParams dp;
    {
        const double sz[5] = {32.0, 64.0, 128.0, 256.0, 512.0};
        const double rt[3] = {0.5, 1.0, 2.0};
        for (int l = 0; l < 5; l++)
            for (int a = 0; a < 3; a++) {
                double hr = sqrt(rt[a]);
                double wr = 1.0 / hr;
                double w = wr * sz[l], h = hr * sz[l];
                dp.b[l][a][0] = (float)nearbyint(-w / 2.0);
                dp.b[l][a][1] = (float)nearbyint(-h / 2.0);
                dp.b[l][a][2] = (float)nearbyint(w / 2.0);
                dp.b[l][a][3] = (float)nearbyint(h / 2.0);
            }
    }
    k_clsfin<<<128, 1024, 0, stream>>>(scores, ghist, key, scr1, scr2, cnts,
                                       deltas, dp, sboxes, sob, svalid);
    k_maskscan<<<(NCAND * WORDS + 1023) / 1024, 1024, 0, stream>>>(
        sob, maskp, svalid, sboxes, (float*)d_out, cnts);
}